// Round 2
// baseline (1286.456 us; speedup 1.0000x reference)
//
#include <hip/hip_runtime.h>
#include <hip/hip_bf16.h>

typedef __hip_bfloat16 bf16;
typedef __attribute__((ext_vector_type(8))) short bf16x8s;
typedef __attribute__((ext_vector_type(4))) float f32x4;

#define NB 64
#define NS 32
#define NV 10000
#define NE 512
#define NH 512
#define NF 2048
#define ND 1024

static __device__ __forceinline__ float bf2f(bf16 x) { return __bfloat162float(x); }
static __device__ __forceinline__ bf16 f2bf(float x) { return __float2bfloat16(x); }

// One 16x16 output tile per wave. A row-major bf16 [*, lda], BT row-major bf16 [N][K].
// mfma_f32_16x16x32_bf16 fragment layout:
//   A: row = lane&15, k = (lane>>4)*8 + j  (8 contiguous bf16 -> one 16B load)
//   B: col = lane&15, k = (lane>>4)*8 + j
//   C/D: col = lane&15, row = (lane>>4)*4 + j   [measured: learn_hip m89]
__device__ __forceinline__ f32x4 wave_tile16(const bf16* A, const bf16* BT,
                                             int lda, int K, int m0, int n0) {
  int lane = threadIdx.x & 63;
  int r = lane & 15, g = lane >> 4;
  const bf16* ap = A + (size_t)(m0 + r) * lda + g * 8;
  const bf16* bp = BT + (size_t)(n0 + r) * K + g * 8;
  f32x4 acc = {0.f, 0.f, 0.f, 0.f};
#pragma unroll 4
  for (int k = 0; k < K; k += 32) {
    bf16x8s a = *(const bf16x8s*)(ap + k);
    bf16x8s b = *(const bf16x8s*)(bp + k);
    acc = __builtin_amdgcn_mfma_f32_16x16x32_bf16(a, b, acc, 0, 0, 0);
  }
  return acc;
}

// ---------------- embedding gather + f32->bf16: x0[b*S+t][:] = bf16(emb[tok][:]) --------
__global__ void k_embed(const int* __restrict__ tokens, const float* __restrict__ emb,
                        bf16* __restrict__ x0) {
  int row = blockIdx.x;            // 0..2047
  int tok = tokens[row];
  const float2* src = (const float2*)(emb + (size_t)tok * NE);
  uint32_t* dst = (uint32_t*)(x0 + (size_t)row * NE);
  float2 v = src[threadIdx.x];     // 256 threads x 2 floats = 512
  __hip_bfloat162 p;
  p.x = f2bf(v.x); p.y = f2bf(v.y);
  dst[threadIdx.x] = *(uint32_t*)&p;
}

// ---------------- f32->bf16 convert (contiguous) ----------------
__global__ void k_cvt(const float* __restrict__ src, bf16* __restrict__ dst, int n) {
  int i = blockIdx.x * 256 + threadIdx.x;
  if (i < n) dst[i] = f2bf(src[i]);
}

// ---------------- transpose + f32->bf16: dst[n][k] = bf16(src[k][n]); src [K][N] --------
__global__ void k_transpose(const float* __restrict__ src, bf16* __restrict__ dst,
                            int K, int N) {
  __shared__ float tile[32][33];
  int n0 = blockIdx.x * 32, k0 = blockIdx.y * 32;
  int tx = threadIdx.x & 31, ty = threadIdx.x >> 5;   // 32x8
  for (int i = ty; i < 32; i += 8) {
    int k = k0 + i, n = n0 + tx;
    tile[i][tx] = (k < K && n < N) ? src[(size_t)k * N + n] : 0.f;
  }
  __syncthreads();
  for (int i = ty; i < 32; i += 8) {
    int n = n0 + i, k = k0 + tx;
    if (n < N && k < K) dst[(size_t)n * K + k] = f2bf(tile[tx][i]);
  }
}

// ---------------- concat 3 gate biases into f32 [1536] ----------------
__global__ void k_bias3(const float* __restrict__ br, const float* __restrict__ bu,
                        const float* __restrict__ bh, float* __restrict__ bias) {
  int i = blockIdx.x * 256 + threadIdx.x;
  if (i < 1536) {
    const float* s = (i < 512) ? (br + i) : (i < 1024 ? (bu + i - 512) : (bh + i - 1024));
    bias[i] = *s;
  }
}

// ---------------- h0 = cnn @ w_in + b_in : [64,2048]@[2048,512], dual-store ------------
__global__ void k_gemm_h0(const bf16* __restrict__ A, const bf16* __restrict__ BT,
                          const float* __restrict__ bias,
                          float* __restrict__ h0f, bf16* __restrict__ h0b) {
  int wid = blockIdx.x * 4 + (threadIdx.x >> 6);  // 128 waves: 4 x 32 tiles
  int mt = wid & 3, nt = wid >> 2;
  f32x4 acc = wave_tile16(A, BT, NF, NF, mt * 16, nt * 16);
  int lane = threadIdx.x & 63;
  int cl = lane & 15, g = lane >> 4;
  int col = nt * 16 + cl;
  float bv = bias[col];
#pragma unroll
  for (int j = 0; j < 4; j++) {
    int row = mt * 16 + g * 4 + j;
    float v = acc[j] + bv;
    h0f[(size_t)row * NH + col] = v;
    h0b[(size_t)row * NH + col] = f2bf(v);
  }
}

// ---------------- pre = X @ Wx_cat + bias3 : [2048,512]@[512,1536] -> f32 ----------------
__global__ void k_gemm_pre(const bf16* __restrict__ A, const bf16* __restrict__ BT,
                           const float* __restrict__ bias, float* __restrict__ pre) {
  int wid = (blockIdx.x * blockDim.x + threadIdx.x) >> 6;  // 12288 waves: 128 x 96 tiles
  int mt = wid % 128, nt = wid / 128;
  f32x4 acc = wave_tile16(A, BT, NE, NE, mt * 16, nt * 16);
  int lane = threadIdx.x & 63;
  int cl = lane & 15, g = lane >> 4;
  int col = nt * 16 + cl;
  float bv = bias[col];
#pragma unroll
  for (int j = 0; j < 4; j++) {
    int row = mt * 16 + g * 4 + j;
    pre[(size_t)row * 1536 + col] = acc[j] + bv;
  }
}

// ---------------- GRU step phase 1: gates r,u ; rh = r*h ----------------
__global__ void k_step1(const bf16* __restrict__ h_b, const float* __restrict__ h_f,
                        const bf16* __restrict__ W_ruh_T, const float* __restrict__ pre,
                        int t, bf16* __restrict__ rh, float* __restrict__ u_buf) {
  int wid = blockIdx.x * 4 + (threadIdx.x >> 6);  // 256 waves: 4 x 64 tiles
  int mt = wid & 3, nt = wid >> 2;
  f32x4 acc = wave_tile16(h_b, W_ruh_T, NH, NH, mt * 16, nt * 16);
  int lane = threadIdx.x & 63;
  int cl = lane & 15, g = lane >> 4;
  int col = nt * 16 + cl;
#pragma unroll
  for (int j = 0; j < 4; j++) {
    int b = mt * 16 + g * 4 + j;
    float pv = pre[(size_t)(b * NS + t) * 1536 + col];
    float gate = 1.f / (1.f + expf(-(acc[j] + pv)));
    if (col < 512) {
      float hv = h_f[b * NH + col];
      rh[b * NH + col] = f2bf(gate * hv);
    } else {
      u_buf[b * NH + (col - 512)] = gate;
    }
  }
}

// ---------------- GRU step phase 2: h_tilde, combine, write h_new + seq ----------------
__global__ void k_step2(const float* __restrict__ h_f, const bf16* __restrict__ rh,
                        const bf16* __restrict__ W_hh_T, const float* __restrict__ pre,
                        const float* __restrict__ u_buf, int t,
                        float* __restrict__ hf_out, bf16* __restrict__ hb_out,
                        bf16* __restrict__ seq) {
  int wid = blockIdx.x * 4 + (threadIdx.x >> 6);  // 128 waves: 4 x 32 tiles
  int mt = wid & 3, nt = wid >> 2;
  f32x4 acc = wave_tile16(rh, W_hh_T, NH, NH, mt * 16, nt * 16);
  int lane = threadIdx.x & 63;
  int cl = lane & 15, g = lane >> 4;
  int col = nt * 16 + cl;
#pragma unroll
  for (int j = 0; j < 4; j++) {
    int b = mt * 16 + g * 4 + j;
    float pv = pre[(size_t)(b * NS + t) * 1536 + 1024 + col];
    float htil = tanhf(acc[j] + pv);
    float u = u_buf[b * NH + col];
    float hold = h_f[b * NH + col];
    float hnew = hold * u + (1.f - u) * htil;
    hf_out[b * NH + col] = hnew;
    hb_out[b * NH + col] = f2bf(hnew);
    seq[(size_t)(b * NS + t) * NH + col] = f2bf(hnew);
  }
}

// ---------------- logits = seq1 @ w_out + b_out : [2048,512]@[512,10000] -> f32 ---------
__global__ void k_gemm_out(const bf16* __restrict__ A, const bf16* __restrict__ BT,
                           const float* __restrict__ bias, float* __restrict__ out) {
  int wid = blockIdx.x * 4 + (threadIdx.x >> 6);  // 32 * 157 = 5024 waves
  int mg = wid % 32, ng = wid / 32;
  int lane = threadIdx.x & 63;
  int cl = lane & 15, g = lane >> 4;
  f32x4 acc[4][4] = {};
  const bf16* a0 = A + (size_t)(mg * 64 + cl) * NE + g * 8;
  const bf16* b0 = BT + (size_t)(ng * 64 + cl) * NE + g * 8;
#pragma unroll 2
  for (int k = 0; k < NE; k += 32) {
    bf16x8s av[4], bv[4];
#pragma unroll
    for (int i = 0; i < 4; i++) av[i] = *(const bf16x8s*)(a0 + (size_t)(i * 16) * NE + k);
#pragma unroll
    for (int i = 0; i < 4; i++) bv[i] = *(const bf16x8s*)(b0 + (size_t)(i * 16) * NE + k);
#pragma unroll
    for (int mi = 0; mi < 4; mi++)
#pragma unroll
      for (int ni = 0; ni < 4; ni++)
        acc[mi][ni] = __builtin_amdgcn_mfma_f32_16x16x32_bf16(av[mi], bv[ni], acc[mi][ni], 0, 0, 0);
  }
#pragma unroll
  for (int mi = 0; mi < 4; mi++) {
#pragma unroll
    for (int ni = 0; ni < 4; ni++) {
      int colb = ng * 64 + ni * 16 + cl;
      if (colb < NV) {
        float bv2 = bias[colb];
#pragma unroll
        for (int j = 0; j < 4; j++) {
          int row = mg * 64 + mi * 16 + g * 4 + j;
          out[(size_t)row * NV + colb] = acc[mi][ni][j] + bv2;
        }
      }
    }
  }
}

extern "C" void kernel_launch(void* const* d_in, const int* in_sizes, int n_in,
                              void* d_out, int out_size, void* d_ws, size_t ws_size,
                              hipStream_t stream) {
  const int*   tokens = (const int*)d_in[0];
  const float* cnn    = (const float*)d_in[1];
  const float* emb    = (const float*)d_in[2];
  const float* w_in   = (const float*)d_in[3];
  const float* b_in   = (const float*)d_in[4];
  const float* w_r    = (const float*)d_in[5];
  const float* b_r    = (const float*)d_in[6];
  const float* w_u    = (const float*)d_in[7];
  const float* b_u    = (const float*)d_in[8];
  const float* w_h    = (const float*)d_in[9];
  const float* b_h    = (const float*)d_in[10];
  const float* w_out  = (const float*)d_in[11];
  const float* b_out  = (const float*)d_in[12];
  float* out = (float*)d_out;

  // ---- workspace carve-up (bytes), 256B aligned ----
  char* ws = (char*)d_ws;
  size_t off = 0;
  auto alloc = [&](size_t bytes) { char* p = ws + off; off += (bytes + 255) & ~(size_t)255; return p; };
  bf16*  x0      = (bf16*) alloc((size_t)2048 * 512 * 2);
  bf16*  seq0    = (bf16*) alloc((size_t)2048 * 512 * 2);
  bf16*  seq1    = (bf16*) alloc((size_t)2048 * 512 * 2);
  float* pre     = (float*)alloc((size_t)2048 * 1536 * 4);
  float* h0f     = (float*)alloc((size_t)64 * 512 * 4);
  bf16*  h0b     = (bf16*) alloc((size_t)64 * 512 * 2);
  float* hf      = (float*)alloc((size_t)64 * 512 * 4);
  bf16*  hb      = (bf16*) alloc((size_t)64 * 512 * 2);
  bf16*  rh      = (bf16*) alloc((size_t)64 * 512 * 2);
  float* u_buf   = (float*)alloc((size_t)64 * 512 * 4);
  float* bias3   = (float*)alloc((size_t)1536 * 4);
  bf16*  cnn_b   = (bf16*) alloc((size_t)64 * 2048 * 2);
  bf16*  w_in_T  = (bf16*) alloc((size_t)512 * 2048 * 2);
  bf16*  w_ruh_T = (bf16*) alloc((size_t)2 * 1024 * 512 * 2);   // per layer: [1024][512]
  bf16*  w_hh_T  = (bf16*) alloc((size_t)2 * 512 * 512 * 2);    // per layer: [512][512]
  bf16*  w_x_T   = (bf16*) alloc((size_t)2 * 1536 * 512 * 2);   // per layer: [1536][512]
  bf16*  w_out_T = (bf16*) alloc((size_t)10048 * 512 * 2);      // padded to 10048 rows
  (void)ws_size; (void)in_sizes; (void)n_in; (void)out_size;

  // zero the w_out_T pad rows so k_gemm_out never loads uninitialized bytes
  hipMemsetAsync(w_out_T + (size_t)10000 * 512, 0, (size_t)48 * 512 * 2, stream);

  // ---- embedding gather (+convert) ----
  k_embed<<<2048, 256, 0, stream>>>(tokens, emb, x0);

  // ---- input converts / weight transposes (f32 -> bf16) ----
  k_cvt<<<512, 256, 0, stream>>>(cnn, cnn_b, 64 * 2048);
  k_transpose<<<dim3(16, 64), 256, 0, stream>>>(w_in, w_in_T, NF, NH);   // [2048,512]->[512][2048]
  for (int l = 0; l < 2; l++) {
    const float* wr = w_r + (size_t)l * ND * NH;
    const float* wu = w_u + (size_t)l * ND * NH;
    const float* wh = w_h + (size_t)l * ND * NH;
    bf16* ruhT = w_ruh_T + (size_t)l * 1024 * 512;
    bf16* hhT  = w_hh_T + (size_t)l * 512 * 512;
    bf16* xT   = w_x_T + (size_t)l * 1536 * 512;
    // h-parts (rows 512..1023 of D)
    k_transpose<<<dim3(16, 16), 256, 0, stream>>>(wr + (size_t)512 * NH, ruhT, 512, 512);
    k_transpose<<<dim3(16, 16), 256, 0, stream>>>(wu + (size_t)512 * NH, ruhT + 512 * 512, 512, 512);
    k_transpose<<<dim3(16, 16), 256, 0, stream>>>(wh + (size_t)512 * NH, hhT, 512, 512);
    // x-parts (rows 0..511 of D)
    k_transpose<<<dim3(16, 16), 256, 0, stream>>>(wr, xT, 512, 512);
    k_transpose<<<dim3(16, 16), 256, 0, stream>>>(wu, xT + 512 * 512, 512, 512);
    k_transpose<<<dim3(16, 16), 256, 0, stream>>>(wh, xT + 1024 * 512, 512, 512);
  }
  // w_out [512,10000] -> [10000][512]
  k_transpose<<<dim3(313, 16), 256, 0, stream>>>(w_out, w_out_T, 512, NV);

  // ---- h0 ----
  k_gemm_h0<<<32, 256, 0, stream>>>(cnn_b, w_in_T, b_in, h0f, h0b);

  // ---- per-layer: precompute x-part GEMM, then 32 recurrent steps ----
  const bf16* seq_in[2] = {x0, seq0};
  bf16* seq_out[2] = {seq0, seq1};
  for (int l = 0; l < 2; l++) {
    k_bias3<<<6, 256, 0, stream>>>(b_r + l * 512, b_u + l * 512, b_h + l * 512, bias3);
    k_gemm_pre<<<3072, 256, 0, stream>>>(seq_in[l], w_x_T + (size_t)l * 1536 * 512, bias3, pre);
    const bf16* ruhT = w_ruh_T + (size_t)l * 1024 * 512;
    const bf16* hhT  = w_hh_T + (size_t)l * 512 * 512;
    for (int t = 0; t < NS; t++) {
      const bf16*  hb_in = (t == 0) ? h0b : hb;
      const float* hf_in = (t == 0) ? h0f : hf;
      k_step1<<<64, 256, 0, stream>>>(hb_in, hf_in, ruhT, pre, t, rh, u_buf);
      k_step2<<<32, 256, 0, stream>>>(hf_in, rh, hhT, pre, u_buf, t, hf, hb, seq_out[l]);
    }
  }

  // ---- logits ----
  k_gemm_out<<<1256, 256, 0, stream>>>(seq1, w_out_T, b_out, out);
}